// Round 7
// baseline (95.642 us; speedup 1.0000x reference)
//
#include <hip/hip_runtime.h>

// AllAtomFAPE: B=2, N_RES=256, N_FR=8, N_AT=14
// out[b] = sum_{f,a} min(sqrt(|Rp^T(xp-tp) - Rt^T(xt-tt)|^2 + eps), 10) * m_fa
//          / (max(sum m_fa, 1) * 10)
//
// Round 5/6/7: SINGLE fused dispatch.
//  - 1024 blocks compute tile partials {num, den} (den hoisted: den = sumFM*sumAM).
//  - Each block publishes its partial (packed u64, agent-scope atomic store)
//    then a per-block 64-bit magic flag (release).
//  - Wave 0 of block 0 spins on all 1024 flags (relaxed agent loads -> one
//    threadfence), gathers partials, fp64-reduces, writes out[2].
//  Robust to arbitrary initial d_ws contents (magic is per-index, 64-bit).

constexpr int B_    = 2;
constexpr int NRES  = 256;
constexpr int NFR   = 8;
constexpr int NAT   = 14;
constexpr int NF    = NRES * NFR;   // 2048 frames per batch
constexpr int NA    = NRES * NAT;   // 3584 atoms per batch

constexpr int FT    = 64;           // frames per block (1 per 4-thread group)
constexpr int ATILE = 224;          // atoms per block tile
constexpr int FBLK  = NF / FT;      // 32
constexpr int ABLK  = NA / ATILE;   // 16
constexpr int BLK_PER_B = FBLK * ABLK;      // 512
constexpr int NBLOCKS   = B_ * BLK_PER_B;   // 1024 blocks -> 4 per CU

#define EPS_F   1e-4f
#define DCLAMP  10.0f

typedef unsigned long long u64;
typedef unsigned int       u32;

__device__ __forceinline__ u64 flag_magic(int idx) {
    return ((u64)(idx + 1) << 32) | 0x5EEDF00DULL;
}

__global__ __launch_bounds__(256, 4) void fape_fused(
    const float* __restrict__ pR,   // [B, NF, 3, 3]
    const float* __restrict__ pT,   // [B, NF, 3]
    const float* __restrict__ pPos, // [B, NA, 3]
    const float* __restrict__ aM,   // [B, NA]
    const float* __restrict__ tR,   // [B, NF, 3, 3]
    const float* __restrict__ tT,   // [B, NF, 3]
    const float* __restrict__ tPos, // [B, NA, 3]
    const float* __restrict__ tAM,  // [B, NA]
    const float* __restrict__ seqM, // [B, NRES]
    const float* __restrict__ frM,  // [B, NF]
    u64* __restrict__ parts,        // [NBLOCKS] packed {num(lo), den(hi)}
    u64* __restrict__ flags,        // [NBLOCKS] publish flags
    float* __restrict__ out)        // [B_]
{
    __shared__ float  sPR[FT * 9];
    __shared__ float  sTR[FT * 9];
    __shared__ float  sPT[FT * 3];
    __shared__ float  sTT[FT * 3];
    __shared__ float  sFM[FT];
    __shared__ float4 sA[ATILE];    // {pred x,y,z, combined atom mask}
    __shared__ float4 sT4[ATILE];   // {true x,y,z, 0}
    __shared__ float  sRed[4 * 3];  // 4 waves x {num, sumAM, sumFM}

    const int bid  = blockIdx.x;
    const int b    = bid / BLK_PER_B;
    const int rem  = bid % BLK_PER_B;
    const int fblk = rem / ABLK;
    const int ablk = rem % ABLK;
    const int f0   = fblk * FT;
    const int a0   = ablk * ATILE;
    const int tid  = threadIdx.x;

    // ---- stage frame tile (coalesced contiguous copies) ----
    {
        const float* gpR = pR + (size_t)(b * NF + f0) * 9;
        const float* gtR = tR + (size_t)(b * NF + f0) * 9;
        for (int i = tid; i < FT * 9; i += 256) { sPR[i] = gpR[i]; sTR[i] = gtR[i]; }
        const float* gpT = pT + (size_t)(b * NF + f0) * 3;
        const float* gtT = tT + (size_t)(b * NF + f0) * 3;
        if (tid < FT * 3) { sPT[tid] = gpT[tid]; sTT[tid] = gtT[tid]; }
        if (tid < FT) {
            const int f = f0 + tid;
            sFM[tid] = seqM[b * NRES + f / NFR] * frM[b * NF + f];
        }
    }
    // ---- stage atom tile, packed as float4 ----
    if (tid < ATILE) {
        const int a = a0 + tid;
        const float* gp = pPos + (size_t)(b * NA + a) * 3;
        const float* gt = tPos + (size_t)(b * NA + a) * 3;
        const float am  = aM[b * NA + a] * tAM[b * NA + a] * seqM[b * NRES + a / NAT];
        sA[tid]  = make_float4(gp[0], gp[1], gp[2], am);
        sT4[tid] = make_float4(gt[0], gt[1], gt[2], 0.f);
    }
    __syncthreads();

    // ---- per-thread frame registers ----
    const int fl  = tid >> 2;   // local frame 0..63
    const int sub = tid & 3;    // atom sub-lane 0..3

    float pr[9], trr[9];
    #pragma unroll
    for (int k = 0; k < 9; ++k) { pr[k] = sPR[fl * 9 + k]; trr[k] = sTR[fl * 9 + k]; }
    const float ptx = sPT[fl * 3 + 0], pty = sPT[fl * 3 + 1], ptz = sPT[fl * 3 + 2];
    const float ttx = sTT[fl * 3 + 0], tty = sTT[fl * 3 + 1], ttz = sTT[fl * 3 + 2];
    const float fm  = sFM[fl];

    float num = 0.f;
    // Each 4-thread group covers all ATILE atoms for its frame. den is NOT
    // accumulated here: den_block = (sum fm) * (sum am), hoisted below.
    #pragma unroll 4
    for (int ai = sub; ai < ATILE; ai += 4) {
        const float4 ap = sA[ai];   // ds_read_b128, 4 distinct addrs/wave
        const float4 tp = sT4[ai];  // ds_read_b128
        const float pdx = ap.x - ptx, pdy = ap.y - pty, pdz = ap.z - ptz;
        const float tdx = tp.x - ttx, tdy = tp.y - tty, tdz = tp.z - ttz;
        // local = R^T * d
        const float lpx = pr[0] * pdx + pr[3] * pdy + pr[6] * pdz;
        const float lpy = pr[1] * pdx + pr[4] * pdy + pr[7] * pdz;
        const float lpz = pr[2] * pdx + pr[5] * pdy + pr[8] * pdz;
        const float ltx = trr[0] * tdx + trr[3] * tdy + trr[6] * tdz;
        const float lty = trr[1] * tdx + trr[4] * tdy + trr[7] * tdz;
        const float ltz = trr[2] * tdx + trr[5] * tdy + trr[8] * tdz;
        const float dx = lpx - ltx, dy = lpy - lty, dz = lpz - ltz;
        float e = __builtin_amdgcn_sqrtf(fmaf(dx, dx, fmaf(dy, dy, fmaf(dz, dz, EPS_F))));
        e = fminf(e, DCLAMP);
        num = fmaf(e, ap.w, num);
    }
    num *= fm;

    // ---- block reduction: 3 channels {num, sumAM, sumFM} ----
    float cAM = (tid < ATILE) ? sA[tid].w : 0.f;
    float cFM = (tid < FT)    ? sFM[tid]  : 0.f;
    #pragma unroll
    for (int off = 32; off > 0; off >>= 1) {
        num += __shfl_down(num, off);
        cAM += __shfl_down(cAM, off);
        cFM += __shfl_down(cFM, off);
    }
    const int wave = tid >> 6;
    if ((tid & 63) == 0) {
        sRed[wave * 3 + 0] = num;
        sRed[wave * 3 + 1] = cAM;
        sRed[wave * 3 + 2] = cFM;
    }
    __syncthreads();
    if (tid == 0) {
        const float n  = sRed[0] + sRed[3] + sRed[6] + sRed[9];
        const float sa = sRed[1] + sRed[4] + sRed[7] + sRed[10];
        const float sf = sRed[2] + sRed[5] + sRed[8] + sRed[11];
        const float d  = sa * sf;
        const u64 packed = (u64)__float_as_uint(n) | ((u64)__float_as_uint(d) << 32);
        __hip_atomic_store(&parts[bid], packed, __ATOMIC_RELAXED, __HIP_MEMORY_SCOPE_AGENT);
        __hip_atomic_store(&flags[bid], flag_magic(bid), __ATOMIC_RELEASE, __HIP_MEMORY_SCOPE_AGENT);
    }

    // ---- block 0, wave 0: gather + final reduce (no second dispatch) ----
    if (bid == 0 && tid < 64) {
        const int lane = tid;
        // Phase 1: wait for all publish flags (relaxed agent loads, coherent).
        #pragma unroll 1
        for (int j = 0; j < NBLOCKS / 64; ++j) {
            const int idx = j * 64 + lane;
            const u64 magic = flag_magic(idx);
            while (__hip_atomic_load(&flags[idx], __ATOMIC_RELAXED,
                                     __HIP_MEMORY_SCOPE_AGENT) != magic) {
                __builtin_amdgcn_s_sleep(8);
            }
        }
        __threadfence();  // acquire: partials ordered behind observed flags
        // Phase 2: gather partials; idx<512 -> b=0, else b=1.
        double n0 = 0.0, d0 = 0.0, n1 = 0.0, d1 = 0.0;
        #pragma unroll 1
        for (int j = 0; j < NBLOCKS / 64; ++j) {
            const int idx = j * 64 + lane;
            const u64 p = __hip_atomic_load(&parts[idx], __ATOMIC_RELAXED,
                                            __HIP_MEMORY_SCOPE_AGENT);
            const float n = __uint_as_float((u32)(p & 0xFFFFFFFFULL));
            const float d = __uint_as_float((u32)(p >> 32));
            if (idx < BLK_PER_B) { n0 += n; d0 += d; }
            else                 { n1 += n; d1 += d; }
        }
        #pragma unroll
        for (int off = 32; off > 0; off >>= 1) {
            n0 += __shfl_down(n0, off);
            d0 += __shfl_down(d0, off);
            n1 += __shfl_down(n1, off);
            d1 += __shfl_down(d1, off);
        }
        if (lane == 0) {
            d0 = d0 > 1.0 ? d0 : 1.0;
            d1 = d1 > 1.0 ? d1 : 1.0;
            out[0] = (float)(n0 / (d0 * 10.0));
            out[1] = (float)(n1 / (d1 * 10.0));
        }
    }
}

extern "C" void kernel_launch(void* const* d_in, const int* in_sizes, int n_in,
                              void* d_out, int out_size, void* d_ws, size_t ws_size,
                              hipStream_t stream)
{
    const float* pR   = (const float*)d_in[0];
    const float* pT   = (const float*)d_in[1];
    const float* pPos = (const float*)d_in[2];
    const float* aM   = (const float*)d_in[3];
    const float* tR   = (const float*)d_in[4];
    const float* tT   = (const float*)d_in[5];
    const float* tPos = (const float*)d_in[6];
    const float* tAM  = (const float*)d_in[7];
    const float* seqM = (const float*)d_in[8];
    const float* frM  = (const float*)d_in[9];

    u64* parts = (u64*)d_ws;              // 8 KiB
    u64* flags = parts + NBLOCKS;         // 8 KiB

    fape_fused<<<NBLOCKS, 256, 0, stream>>>(pR, pT, pPos, aM, tR, tT, tPos, tAM,
                                            seqM, frM, parts, flags, (float*)d_out);
}

// Round 9
// 86.229 us; speedup vs baseline: 1.1092x; 1.1092x over previous
//
#include <hip/hip_runtime.h>

// AllAtomFAPE: B=2, N_RES=256, N_FR=8, N_AT=14
// out[b] = sum_{f,a} min(sqrt(|Rp^T(xp-tp) - Rt^T(xt-tt)|^2 + eps), 10) * m_fa
//          / (max(sum m_fa, 1) * 10)
//
// Round 8/9: single fused dispatch (structure benched neutral vs 2-dispatch,
// kept for simplicity) + two targeted cuts:
//  (a) inner loop algebra: e = Rp^T xp - Rt^T xt + c, c per-frame
//      (c = Rt^T tt - Rp^T tp), Rt negated per-frame -> one 18-FMA chain
//      + 3-FMA norm + sqrt/min/fma  ~= 24 VALU/pair (was ~33).
//  (b) block-0 tail: vectorized flag sweeps (16 pipelined loads per sweep)
//      instead of per-flag serial spin; pipelined 16-load gather.

constexpr int B_    = 2;
constexpr int NRES  = 256;
constexpr int NFR   = 8;
constexpr int NAT   = 14;
constexpr int NF    = NRES * NFR;   // 2048 frames per batch
constexpr int NA    = NRES * NAT;   // 3584 atoms per batch

constexpr int FT    = 64;           // frames per block (1 per 4-thread group)
constexpr int ATILE = 224;          // atoms per block tile
constexpr int FBLK  = NF / FT;      // 32
constexpr int ABLK  = NA / ATILE;   // 16
constexpr int BLK_PER_B = FBLK * ABLK;      // 512
constexpr int NBLOCKS   = B_ * BLK_PER_B;   // 1024 blocks -> 4 per CU (co-resident)
constexpr int NSEG      = NBLOCKS / 64;     // 16 flag segments per lane

#define EPS_F   1e-4f
#define DCLAMP  10.0f

typedef unsigned long long u64;
typedef unsigned int       u32;

__device__ __forceinline__ u64 flag_magic(int idx) {
    return ((u64)(idx + 1) << 32) | 0x5EEDF00DULL;
}

__global__ __launch_bounds__(256, 4) void fape_fused(
    const float* __restrict__ pR,   // [B, NF, 3, 3]
    const float* __restrict__ pT,   // [B, NF, 3]
    const float* __restrict__ pPos, // [B, NA, 3]
    const float* __restrict__ aM,   // [B, NA]
    const float* __restrict__ tR,   // [B, NF, 3, 3]
    const float* __restrict__ tT,   // [B, NF, 3]
    const float* __restrict__ tPos, // [B, NA, 3]
    const float* __restrict__ tAM,  // [B, NA]
    const float* __restrict__ seqM, // [B, NRES]
    const float* __restrict__ frM,  // [B, NF]
    u64* __restrict__ parts,        // [NBLOCKS] packed {num(lo), den(hi)}
    u64* __restrict__ flags,        // [NBLOCKS] publish flags
    float* __restrict__ out)        // [B_]
{
    __shared__ float  sPR[FT * 9];
    __shared__ float  sTR[FT * 9];
    __shared__ float  sPT[FT * 3];
    __shared__ float  sTT[FT * 3];
    __shared__ float  sFM[FT];
    __shared__ float4 sA[ATILE];    // {pred x,y,z, combined atom mask}
    __shared__ float4 sT4[ATILE];   // {true x,y,z, 0}
    __shared__ float  sRed[4 * 3];  // 4 waves x {num, sumAM, sumFM}

    const int bid  = blockIdx.x;
    const int b    = bid / BLK_PER_B;
    const int rem  = bid % BLK_PER_B;
    const int fblk = rem / ABLK;
    const int ablk = rem % ABLK;
    const int f0   = fblk * FT;
    const int a0   = ablk * ATILE;
    const int tid  = threadIdx.x;

    // ---- stage frame tile (coalesced contiguous copies) ----
    {
        const float* gpR = pR + (size_t)(b * NF + f0) * 9;
        const float* gtR = tR + (size_t)(b * NF + f0) * 9;
        for (int i = tid; i < FT * 9; i += 256) { sPR[i] = gpR[i]; sTR[i] = gtR[i]; }
        const float* gpT = pT + (size_t)(b * NF + f0) * 3;
        const float* gtT = tT + (size_t)(b * NF + f0) * 3;
        if (tid < FT * 3) { sPT[tid] = gpT[tid]; sTT[tid] = gtT[tid]; }
        if (tid < FT) {
            const int f = f0 + tid;
            sFM[tid] = seqM[b * NRES + f / NFR] * frM[b * NF + f];
        }
    }
    // ---- stage atom tile, packed as float4 ----
    if (tid < ATILE) {
        const int a = a0 + tid;
        const float* gp = pPos + (size_t)(b * NA + a) * 3;
        const float* gt = tPos + (size_t)(b * NA + a) * 3;
        const float am  = aM[b * NA + a] * tAM[b * NA + a] * seqM[b * NRES + a / NAT];
        sA[tid]  = make_float4(gp[0], gp[1], gp[2], am);
        sT4[tid] = make_float4(gt[0], gt[1], gt[2], 0.f);
    }
    __syncthreads();

    // ---- per-thread frame registers ----
    const int fl  = tid >> 2;   // local frame 0..63
    const int sub = tid & 3;    // atom sub-lane 0..3

    float pr[9], ntr[9];
    #pragma unroll
    for (int k = 0; k < 9; ++k) { pr[k] = sPR[fl * 9 + k]; ntr[k] = -sTR[fl * 9 + k]; }
    const float ptx = sPT[fl * 3 + 0], pty = sPT[fl * 3 + 1], ptz = sPT[fl * 3 + 2];
    const float ttx = sTT[fl * 3 + 0], tty = sTT[fl * 3 + 1], ttz = sTT[fl * 3 + 2];
    const float fm  = sFM[fl];

    // Per-frame constant: c = Rt^T tt - Rp^T tp   (ntr = -Rt row-major)
    // local_i = sum_r R[r][i] v_r  -> column i uses regs {i, i+3, i+6}
    const float cx = -(ntr[0] * ttx + ntr[3] * tty + ntr[6] * ttz)
                     - (pr[0] * ptx + pr[3] * pty + pr[6] * ptz);
    const float cy = -(ntr[1] * ttx + ntr[4] * tty + ntr[7] * ttz)
                     - (pr[1] * ptx + pr[4] * pty + pr[7] * ptz);
    const float cz = -(ntr[2] * ttx + ntr[5] * tty + ntr[8] * ttz)
                     - (pr[2] * ptx + pr[5] * pty + pr[8] * ptz);

    float num = 0.f;
    // e_i = (Rp^T xp)_i - (Rt^T xt)_i + c_i  as one 6-FMA chain per component.
    #pragma unroll 4
    for (int ai = sub; ai < ATILE; ai += 4) {
        const float4 ap = sA[ai];   // ds_read_b128, 4-lane broadcast groups
        const float4 tp = sT4[ai];  // ds_read_b128
        const float ex = fmaf(pr[0], ap.x, fmaf(pr[3], ap.y, fmaf(pr[6], ap.z,
                         fmaf(ntr[0], tp.x, fmaf(ntr[3], tp.y, fmaf(ntr[6], tp.z, cx))))));
        const float ey = fmaf(pr[1], ap.x, fmaf(pr[4], ap.y, fmaf(pr[7], ap.z,
                         fmaf(ntr[1], tp.x, fmaf(ntr[4], tp.y, fmaf(ntr[7], tp.z, cy))))));
        const float ez = fmaf(pr[2], ap.x, fmaf(pr[5], ap.y, fmaf(pr[8], ap.z,
                         fmaf(ntr[2], tp.x, fmaf(ntr[5], tp.y, fmaf(ntr[8], tp.z, cz))))));
        float e = __builtin_amdgcn_sqrtf(fmaf(ex, ex, fmaf(ey, ey, fmaf(ez, ez, EPS_F))));
        e = fminf(e, DCLAMP);
        num = fmaf(e, ap.w, num);
    }
    num *= fm;

    // ---- block reduction: 3 channels {num, sumAM, sumFM}; den = sumAM*sumFM ----
    float cAM = (tid < ATILE) ? sA[tid].w : 0.f;
    float cFM = (tid < FT)    ? sFM[tid]  : 0.f;
    #pragma unroll
    for (int off = 32; off > 0; off >>= 1) {
        num += __shfl_down(num, off);
        cAM += __shfl_down(cAM, off);
        cFM += __shfl_down(cFM, off);
    }
    const int wave = tid >> 6;
    if ((tid & 63) == 0) {
        sRed[wave * 3 + 0] = num;
        sRed[wave * 3 + 1] = cAM;
        sRed[wave * 3 + 2] = cFM;
    }
    __syncthreads();
    if (tid == 0) {
        const float n  = sRed[0] + sRed[3] + sRed[6] + sRed[9];
        const float sa = sRed[1] + sRed[4] + sRed[7] + sRed[10];
        const float sf = sRed[2] + sRed[5] + sRed[8] + sRed[11];
        const float d  = sa * sf;
        const u64 packed = (u64)__float_as_uint(n) | ((u64)__float_as_uint(d) << 32);
        __hip_atomic_store(&parts[bid], packed, __ATOMIC_RELAXED, __HIP_MEMORY_SCOPE_AGENT);
        __hip_atomic_store(&flags[bid], flag_magic(bid), __ATOMIC_RELEASE, __HIP_MEMORY_SCOPE_AGENT);
    }

    // ---- block 0, wave 0: gather + final reduce (no second dispatch) ----
    if (bid == 0 && tid < 64) {
        const int lane = tid;
        // Phase 1: vectorized flag sweeps — 16 independent loads per sweep
        // (one L2 latency per sweep instead of 16 serial ones).
        bool ready = false;
        while (!ready) {
            u64 v[NSEG];
            #pragma unroll
            for (int j = 0; j < NSEG; ++j)
                v[j] = __hip_atomic_load(&flags[j * 64 + lane], __ATOMIC_RELAXED,
                                         __HIP_MEMORY_SCOPE_AGENT);
            bool ok = true;
            #pragma unroll
            for (int j = 0; j < NSEG; ++j)
                ok &= (v[j] == flag_magic(j * 64 + lane));
            ready = __all(ok);
            if (!ready) __builtin_amdgcn_s_sleep(1);
        }
        __threadfence();  // acquire: partials ordered behind observed flags
        // Phase 2: pipelined gather of all partials; idx<512 -> b=0, else b=1.
        u64 p[NSEG];
        #pragma unroll
        for (int j = 0; j < NSEG; ++j)
            p[j] = __hip_atomic_load(&parts[j * 64 + lane], __ATOMIC_RELAXED,
                                     __HIP_MEMORY_SCOPE_AGENT);
        double n0 = 0.0, d0 = 0.0, n1 = 0.0, d1 = 0.0;
        #pragma unroll
        for (int j = 0; j < NSEG; ++j) {
            const float n = __uint_as_float((u32)(p[j] & 0xFFFFFFFFULL));
            const float d = __uint_as_float((u32)(p[j] >> 32));
            if (j < NSEG / 2) { n0 += n; d0 += d; }   // idx = j*64+lane < 512
            else              { n1 += n; d1 += d; }
        }
        #pragma unroll
        for (int off = 32; off > 0; off >>= 1) {
            n0 += __shfl_down(n0, off);
            d0 += __shfl_down(d0, off);
            n1 += __shfl_down(n1, off);
            d1 += __shfl_down(d1, off);
        }
        if (lane == 0) {
            d0 = d0 > 1.0 ? d0 : 1.0;
            d1 = d1 > 1.0 ? d1 : 1.0;
            out[0] = (float)(n0 / (d0 * 10.0));
            out[1] = (float)(n1 / (d1 * 10.0));
        }
    }
}

extern "C" void kernel_launch(void* const* d_in, const int* in_sizes, int n_in,
                              void* d_out, int out_size, void* d_ws, size_t ws_size,
                              hipStream_t stream)
{
    const float* pR   = (const float*)d_in[0];
    const float* pT   = (const float*)d_in[1];
    const float* pPos = (const float*)d_in[2];
    const float* aM   = (const float*)d_in[3];
    const float* tR   = (const float*)d_in[4];
    const float* tT   = (const float*)d_in[5];
    const float* tPos = (const float*)d_in[6];
    const float* tAM  = (const float*)d_in[7];
    const float* seqM = (const float*)d_in[8];
    const float* frM  = (const float*)d_in[9];

    u64* parts = (u64*)d_ws;              // 8 KiB
    u64* flags = parts + NBLOCKS;         // 8 KiB

    fape_fused<<<NBLOCKS, 256, 0, stream>>>(pR, pT, pPos, aM, tR, tT, tPos, tAM,
                                            seqM, frM, parts, flags, (float*)d_out);
}